// Round 2
// baseline (698.857 us; speedup 1.0000x reference)
//
#include <hip/hip_runtime.h>
#include <hip/hip_bf16.h>
#include <math.h>

#define S_LEN 2048
#define NH    32
#define NKV   8
#define HD    64
#define HID2  4096   // 2*HID (K of projections)
#define HIDQ  2048   // H*D
#define HIDK  512    // HK*D

typedef __attribute__((ext_vector_type(8))) __bf16 bf16x8;
typedef __attribute__((ext_vector_type(4))) __bf16 bf16x4;
typedef __attribute__((ext_vector_type(4))) float  f32x4;

__device__ __forceinline__ f32x4 mfma16(bf16x8 a, bf16x8 b, f32x4 c) {
  return __builtin_amdgcn_mfma_f32_16x16x32_bf16(a, b, c, 0, 0, 0);
}

__device__ __forceinline__ void gload_lds16(const void* g, void* l) {
  __builtin_amdgcn_global_load_lds(
      (const __attribute__((address_space(1))) void*)g,
      (__attribute__((address_space(3))) void*)l, 16, 0, 0);
}

// ---------------- cast f32 -> bf16 (vectorized) ----------------
__global__ __launch_bounds__(256) void cast_bf16_k(const float* __restrict__ src,
                                                   __bf16* __restrict__ dst, int n4) {
  int i = blockIdx.x * 256 + threadIdx.x;
  if (i >= n4) return;
  float4 v = reinterpret_cast<const float4*>(src)[i];
  bf16x4 o;
  o.x = (__bf16)v.x; o.y = (__bf16)v.y; o.z = (__bf16)v.z; o.w = (__bf16)v.w;
  reinterpret_cast<bf16x4*>(dst)[i] = o;
}

// ---------------- RoPE cos/sin table: cs[s*32+j] = (cos, sin) ----------------
__global__ __launch_bounds__(256) void rope_table_k(const int* __restrict__ pos,
                                                    float2* __restrict__ cs) {
  int s = blockIdx.x * blockDim.x + threadIdx.x;
  if (s >= S_LEN) return;
  float p = (float)pos[s];
  for (int j = 0; j < 32; ++j) {
    float inv = 1.0f / powf(10000.0f, (float)j * (1.0f / 32.0f));
    float ang = p * inv;                 // f32 angle, same rounding as reference
    double a = (double)ang;              // accurate trig on that angle
    cs[s * 32 + j] = make_float2((float)cos(a), (float)sin(a));
  }
}

// ---------------- GEMM: C[M,N] = A[M,K] @ B[N,K]^T ----------------
// EPI: 1 = RoPE + bf16 store (Q/K proj), 2 = transpose bf16 store (V -> Vt[n][m]),
//      3 = f32 store (final output)
template <int EPI>
__global__ __launch_bounds__(256) void gemm_bt(const __bf16* __restrict__ A,
                                               const __bf16* __restrict__ B,
                                               void* __restrict__ outp,
                                               int M, int N, int K,
                                               const float2* __restrict__ cs) {
  __shared__ __align__(16) __bf16 Abuf[128 * 32];
  __shared__ __align__(16) __bf16 Bbuf[128 * 32];
  const int tid = threadIdx.x;
  const int w = tid >> 6, l = tid & 63;
  const int wr = w >> 1, wc = w & 1;
  const int row0 = blockIdx.y * 128, col0 = blockIdx.x * 128;
  const int lr = l & 15, lk = (l >> 4) * 8;

  f32x4 acc[4][4] = {};

  const __bf16* Ag = A + (size_t)(row0 + (tid >> 2)) * K + (tid & 3) * 8;
  const __bf16* Bg = B + (size_t)(col0 + (tid >> 2)) * K + (tid & 3) * 8;
  __bf16* AbufW = Abuf + w * 512;
  __bf16* BbufW = Bbuf + w * 512;

  for (int kt = 0; kt < K; kt += 32) {
    gload_lds16(Ag + kt, AbufW);
    gload_lds16(Ag + kt + (size_t)64 * K, AbufW + 2048);
    gload_lds16(Bg + kt, BbufW);
    gload_lds16(Bg + kt + (size_t)64 * K, BbufW + 2048);
    __syncthreads();
    bf16x8 af[4], bfr[4];
#pragma unroll
    for (int i = 0; i < 4; ++i)
      af[i] = *reinterpret_cast<const bf16x8*>(&Abuf[(64 * wr + 16 * i + lr) * 32 + lk]);
#pragma unroll
    for (int j = 0; j < 4; ++j)
      bfr[j] = *reinterpret_cast<const bf16x8*>(&Bbuf[(64 * wc + 16 * j + lr) * 32 + lk]);
#pragma unroll
    for (int i = 0; i < 4; ++i)
#pragma unroll
      for (int j = 0; j < 4; ++j)
        acc[i][j] = mfma16(af[i], bfr[j], acc[i][j]);
    __syncthreads();
  }

  const int mb = row0 + 64 * wr, nb = col0 + 64 * wc;
  const int rsub = (l >> 4) * 4;

  if constexpr (EPI == 1) {
    __bf16* out = (__bf16*)outp;
#pragma unroll
    for (int i = 0; i < 4; ++i)
#pragma unroll
      for (int r = 0; r < 4; ++r) {
        int m = mb + 16 * i + rsub + r;
#pragma unroll
        for (int j = 0; j < 2; ++j) {
          int d = 16 * j + lr;  // d in [0,32): nb is 64-aligned
          float2 c = cs[m * 32 + d];
          float x1 = acc[i][j][r];
          float x2 = acc[i][j + 2][r];
          out[(size_t)m * N + nb + d]      = (__bf16)(x1 * c.x - x2 * c.y);
          out[(size_t)m * N + nb + d + 32] = (__bf16)(x2 * c.x + x1 * c.y);
        }
      }
  } else if constexpr (EPI == 2) {
    __bf16* out = (__bf16*)outp;  // out[n * M + m]
#pragma unroll
    for (int i = 0; i < 4; ++i)
#pragma unroll
      for (int j = 0; j < 4; ++j)
#pragma unroll
        for (int r = 0; r < 4; ++r)
          out[(size_t)(nb + 16 * j + lr) * M + mb + 16 * i + rsub + r] =
              (__bf16)acc[i][j][r];
  } else {
    float* out = (float*)outp;
#pragma unroll
    for (int i = 0; i < 4; ++i)
#pragma unroll
      for (int j = 0; j < 4; ++j)
#pragma unroll
      for (int r = 0; r < 4; ++r)
          out[(size_t)(mb + 16 * i + rsub + r) * N + nb + 16 * j + lr] = acc[i][j][r];
  }
}

// ---------------- flash attention (causal, GQA 4:1) ----------------
// Q: [S, 2048] bf16 (RoPE'd)   K: [S, 512] bf16 (RoPE'd)
// Vt: [512, S] bf16 (Vt[kh*64+d][s])   AO: [S, 2048] bf16
__global__ __launch_bounds__(256) void attn_k(const __bf16* __restrict__ Q,
                                              const __bf16* __restrict__ Kc,
                                              const __bf16* __restrict__ Vt,
                                              __bf16* __restrict__ AO) {
  __shared__ __align__(16) __bf16 Pl[4][16][72];  // per-wave P tile, padded
  const int w = threadIdx.x >> 6, l = threadIdx.x & 63;
  const int qt = blockIdx.x, h = blockIdx.y;
  const int kh = h >> 2;  // G = 4
  const int qbase = qt * 64 + w * 16;
  const int lr = l & 15, lg = l >> 4;

  bf16x8 qf[2];
  {
    const __bf16* qp = Q + (size_t)(qbase + lr) * HIDQ + h * HD + lg * 8;
    qf[0] = *reinterpret_cast<const bf16x8*>(qp);
    qf[1] = *reinterpret_cast<const bf16x8*>(qp + 32);
  }
  f32x4 o[4] = {};
  float mrun[4], lrun[4];
#pragma unroll
  for (int r = 0; r < 4; ++r) { mrun[r] = -3e38f; lrun[r] = 0.f; }

  for (int t = 0; t <= qt; ++t) {
    const int kv0 = t * 64;
    f32x4 sc[4] = {};
    const __bf16* kp = Kc + (size_t)(kv0 + lr) * HIDK + kh * HD + lg * 8;
#pragma unroll
    for (int n = 0; n < 4; ++n) {
      bf16x8 k0 = *reinterpret_cast<const bf16x8*>(kp + (size_t)n * 16 * HIDK);
      bf16x8 k1 = *reinterpret_cast<const bf16x8*>(kp + (size_t)n * 16 * HIDK + 32);
      sc[n] = mfma16(qf[0], k0, sc[n]);
      sc[n] = mfma16(qf[1], k1, sc[n]);
    }
    const bool diag = (t == qt);
    float mx[4];
#pragma unroll
    for (int r = 0; r < 4; ++r) {
#pragma unroll
      for (int n = 0; n < 4; ++n) {
        float v = sc[n][r] * 0.125f;  // D^-0.5
        if (diag && (kv0 + 16 * n + lr > qbase + lg * 4 + r)) v = -3e38f;
        sc[n][r] = v;
      }
      float m0 = fmaxf(fmaxf(sc[0][r], sc[1][r]), fmaxf(sc[2][r], sc[3][r]));
      m0 = fmaxf(m0, __shfl_xor(m0, 1));
      m0 = fmaxf(m0, __shfl_xor(m0, 2));
      m0 = fmaxf(m0, __shfl_xor(m0, 4));
      m0 = fmaxf(m0, __shfl_xor(m0, 8));
      mx[r] = m0;
    }
#pragma unroll
    for (int r = 0; r < 4; ++r) {
      float mnew = fmaxf(mrun[r], mx[r]);
      float a = __expf(mrun[r] - mnew);
      lrun[r] *= a;
#pragma unroll
      for (int j = 0; j < 4; ++j) o[j][r] *= a;
      float sum = 0.f;
#pragma unroll
      for (int n = 0; n < 4; ++n) {
        float p = __expf(sc[n][r] - mnew);
        sc[n][r] = p;
        sum += p;
      }
      sum += __shfl_xor(sum, 1);
      sum += __shfl_xor(sum, 2);
      sum += __shfl_xor(sum, 4);
      sum += __shfl_xor(sum, 8);
      lrun[r] += sum;
      mrun[r] = mnew;
    }
    // P (C-layout) -> LDS -> A-frag layout
#pragma unroll
    for (int n = 0; n < 4; ++n)
#pragma unroll
      for (int r = 0; r < 4; ++r)
        Pl[w][lg * 4 + r][lr + 16 * n] = (__bf16)sc[n][r];
    bf16x8 pa0 = *reinterpret_cast<const bf16x8*>(&Pl[w][lr][lg * 8]);
    bf16x8 pa1 = *reinterpret_cast<const bf16x8*>(&Pl[w][lr][lg * 8 + 32]);
    const __bf16* vp = Vt + (size_t)(kh * HD + lr) * S_LEN + kv0 + lg * 8;
#pragma unroll
    for (int j = 0; j < 4; ++j) {
      bf16x8 v0 = *reinterpret_cast<const bf16x8*>(vp + (size_t)j * 16 * S_LEN);
      bf16x8 v1 = *reinterpret_cast<const bf16x8*>(vp + (size_t)j * 16 * S_LEN + 32);
      o[j] = mfma16(pa0, v0, o[j]);
      o[j] = mfma16(pa1, v1, o[j]);
    }
  }
#pragma unroll
  for (int j = 0; j < 4; ++j)
#pragma unroll
    for (int r = 0; r < 4; ++r)
      AO[(size_t)(qbase + lg * 4 + r) * HIDQ + h * HD + 16 * j + lr] =
          (__bf16)(o[j][r] / lrun[r]);
}

extern "C" void kernel_launch(void* const* d_in, const int* in_sizes, int n_in,
                              void* d_out, int out_size, void* d_ws, size_t ws_size,
                              hipStream_t stream) {
  const float* hs = (const float*)d_in[0];
  const int*   pos = (const int*)d_in[1];
  const float* wq = (const float*)d_in[2];
  const float* wk = (const float*)d_in[3];
  const float* wv = (const float*)d_in[4];
  const float* wo = (const float*)d_in[5];

  char* ws = (char*)d_ws;
  const size_t MB = (size_t)1 << 20;
  __bf16* Xbf = (__bf16*)(ws + 0 * MB);    // 16 MB  [2048 x 4096]
  __bf16* WQb = (__bf16*)(ws + 16 * MB);   // 16 MB  [2048 x 4096]
  __bf16* WKb = (__bf16*)(ws + 32 * MB);   //  4 MB  [512 x 4096]
  __bf16* WVb = (__bf16*)(ws + 36 * MB);   //  4 MB  [512 x 4096]
  __bf16* WOb = (__bf16*)(ws + 40 * MB);   //  8 MB  [2048 x 2048]
  __bf16* Qb  = (__bf16*)(ws + 48 * MB);   //  8 MB  [2048 x 2048]
  __bf16* Kb  = (__bf16*)(ws + 56 * MB);   //  2 MB  [2048 x 512]
  __bf16* Vt  = (__bf16*)(ws + 58 * MB);   //  2 MB  [512 x 2048]
  __bf16* AOb = (__bf16*)(ws + 60 * MB);   //  8 MB  [2048 x 2048]
  float2* CS  = (float2*)(ws + 68 * MB);   // 512 KB [2048 x 32]

  auto cast = [&](const float* s, __bf16* d, int n) {
    int n4 = n / 4;
    cast_bf16_k<<<(n4 + 255) / 256, 256, 0, stream>>>(s, d, n4);
  };
  cast(hs, Xbf, S_LEN * HID2);
  cast(wq, WQb, HIDQ * HID2);
  cast(wk, WKb, HIDK * HID2);
  cast(wv, WVb, HIDK * HID2);
  cast(wo, WOb, 2048 * HIDQ);
  rope_table_k<<<(S_LEN + 255) / 256, 256, 0, stream>>>(pos, CS);

  // Q/K projections with fused RoPE, V projection with fused transpose
  gemm_bt<1><<<dim3(HIDQ / 128, S_LEN / 128), 256, 0, stream>>>(
      Xbf, WQb, Qb, S_LEN, HIDQ, HID2, CS);
  gemm_bt<1><<<dim3(HIDK / 128, S_LEN / 128), 256, 0, stream>>>(
      Xbf, WKb, Kb, S_LEN, HIDK, HID2, CS);
  gemm_bt<2><<<dim3(HIDK / 128, S_LEN / 128), 256, 0, stream>>>(
      Xbf, WVb, Vt, S_LEN, HIDK, HID2, nullptr);

  attn_k<<<dim3(S_LEN / 64, NH), 256, 0, stream>>>(Qb, Kb, Vt, AOb);

  // final projection, f32 output
  gemm_bt<3><<<dim3(HIDQ / 128, S_LEN / 128), 256, 0, stream>>>(
      AOb, WOb, d_out, S_LEN, HIDQ, HIDQ, nullptr);
}

// Round 5
// 385.208 us; speedup vs baseline: 1.8142x; 1.8142x over previous
//
#include <hip/hip_runtime.h>
#include <hip/hip_bf16.h>
#include <math.h>

#define S_LEN 2048
#define NH    32
#define NKV   8
#define HD    64
#define HID2  4096   // 2*HID (K of projections)
#define HIDQ  2048   // H*D
#define HIDK  512    // HK*D

typedef __attribute__((ext_vector_type(8))) __bf16 bf16x8;
typedef __attribute__((ext_vector_type(4))) __bf16 bf16x4;
typedef __attribute__((ext_vector_type(4))) float  f32x4;

__device__ __forceinline__ f32x4 mfma16(bf16x8 a, bf16x8 b, f32x4 c) {
  return __builtin_amdgcn_mfma_f32_16x16x32_bf16(a, b, c, 0, 0, 0);
}

__device__ __forceinline__ void gload_lds16(const void* g, void* l) {
  __builtin_amdgcn_global_load_lds(
      (const __attribute__((address_space(1))) void*)g,
      (__attribute__((address_space(3))) void*)l, 16, 0, 0);
}

__device__ __forceinline__ unsigned int packbf(float a, float b) {
  __bf16 ba = (__bf16)a, bb = (__bf16)b;
  unsigned short ua = __builtin_bit_cast(unsigned short, ba);
  unsigned short ub = __builtin_bit_cast(unsigned short, bb);
  return (unsigned int)ua | ((unsigned int)ub << 16);
}

// ---------------- merged cast f32 -> bf16 (all 5 tensors, contiguous dst) ----
#define F4_HS 2097152
#define F4_WQ 2097152
#define F4_WK 524288
#define F4_WV 524288
#define F4_WO 1048576
#define F4_TOT (F4_HS + F4_WQ + F4_WK + F4_WV + F4_WO)  // 6291456

__global__ __launch_bounds__(256) void cast_all_k(
    const float* __restrict__ hs, const float* __restrict__ wq,
    const float* __restrict__ wk, const float* __restrict__ wv,
    const float* __restrict__ wo, bf16x4* __restrict__ dst) {
  int i = blockIdx.x * 256 + threadIdx.x;
  if (i >= F4_TOT) return;
  const float* src;
  int off = i;
  if (off < F4_HS) { src = hs; }
  else { off -= F4_HS;
    if (off < F4_WQ) { src = wq; }
    else { off -= F4_WQ;
      if (off < F4_WK) { src = wk; }
      else { off -= F4_WK;
        if (off < F4_WV) { src = wv; }
        else { off -= F4_WV; src = wo; } } } }
  float4 v = reinterpret_cast<const float4*>(src)[off];
  bf16x4 o;
  o[0] = (__bf16)v.x; o[1] = (__bf16)v.y; o[2] = (__bf16)v.z; o[3] = (__bf16)v.w;
  dst[i] = o;
}

// ---------------- RoPE cos/sin table: cs[s*32+j] = (cos, sin) ----------------
__global__ __launch_bounds__(256) void rope_table_k(const int* __restrict__ pos,
                                                    float2* __restrict__ cs) {
  int idx = blockIdx.x * 256 + threadIdx.x;
  if (idx >= S_LEN * 32) return;
  int s = idx >> 5, j = idx & 31;
  float p = (float)pos[s];
  // inv_freq = 10000^(-j/32) via exp2
  float inv = exp2f(-(float)j * (13.287712379549449f / 32.0f));
  float ang = p * inv;
  float sv, cv;
  sincosf(ang, &sv, &cv);
  cs[idx] = make_float2(cv, sv);
}

// ---------------- merged QKV projection GEMM ----------------
// A[2048,4096] bf16, B[3072,4096] bf16 (rows: 0-2047 WQ, 2048-2559 WK, 2560-3071 WV)
// epilogue per 128-col tile: Q-RoPE -> Qo, K-RoPE -> Ko, V-transpose -> Vto
__global__ __launch_bounds__(256) void gemm_qkv(
    const __bf16* __restrict__ A, const __bf16* __restrict__ B,
    __bf16* __restrict__ Qo, __bf16* __restrict__ Ko, __bf16* __restrict__ Vto,
    const float2* __restrict__ cs) {
  const int K = HID2;
  __shared__ __align__(16) __bf16 Abuf[128 * 32];
  __shared__ __align__(16) __bf16 Bbuf[128 * 32];
  const int tid = threadIdx.x;
  const int w = tid >> 6, l = tid & 63;
  const int wr = w >> 1, wc = w & 1;
  const int row0 = blockIdx.y * 128, col0 = blockIdx.x * 128;
  const int lr = l & 15, lk = (l >> 4) * 8;

  f32x4 acc[4][4] = {};

  const __bf16* Ag = A + (size_t)(row0 + (tid >> 2)) * K + (tid & 3) * 8;
  const __bf16* Bg = B + (size_t)(col0 + (tid >> 2)) * K + (tid & 3) * 8;
  __bf16* AbufW = Abuf + w * 512;
  __bf16* BbufW = Bbuf + w * 512;

  for (int kt = 0; kt < K; kt += 32) {
    gload_lds16(Ag + kt, AbufW);
    gload_lds16(Ag + kt + (size_t)64 * K, AbufW + 2048);
    gload_lds16(Bg + kt, BbufW);
    gload_lds16(Bg + kt + (size_t)64 * K, BbufW + 2048);
    __syncthreads();
    bf16x8 af[4], bfr[4];
#pragma unroll
    for (int i = 0; i < 4; ++i)
      af[i] = *reinterpret_cast<const bf16x8*>(&Abuf[(64 * wr + 16 * i + lr) * 32 + lk]);
#pragma unroll
    for (int j = 0; j < 4; ++j)
      bfr[j] = *reinterpret_cast<const bf16x8*>(&Bbuf[(64 * wc + 16 * j + lr) * 32 + lk]);
#pragma unroll
    for (int i = 0; i < 4; ++i)
#pragma unroll
      for (int j = 0; j < 4; ++j)
        acc[i][j] = mfma16(af[i], bfr[j], acc[i][j]);
    __syncthreads();
  }

  const int mb = row0 + 64 * wr, nb = col0 + 64 * wc;
  const int rsub = (l >> 4) * 4;

  if (col0 < 2560) {  // Q or K: RoPE epilogue
    __bf16* out;
    int ostride, ncol;
    if (col0 < 2048) { out = Qo; ostride = HIDQ; ncol = nb; }
    else             { out = Ko; ostride = HIDK; ncol = nb - 2048; }
#pragma unroll
    for (int i = 0; i < 4; ++i)
#pragma unroll
      for (int r = 0; r < 4; ++r) {
        int m = mb + 16 * i + rsub + r;
#pragma unroll
        for (int j = 0; j < 2; ++j) {
          int d = 16 * j + lr;  // within-head dim (ncol is 64-aligned)
          float2 c = cs[m * 32 + d];
          float x1 = acc[i][j][r];
          float x2 = acc[i][j + 2][r];
          out[(size_t)m * ostride + ncol + d]      = (__bf16)(x1 * c.x - x2 * c.y);
          out[(size_t)m * ostride + ncol + d + 32] = (__bf16)(x2 * c.x + x1 * c.y);
        }
      }
  } else {  // V: transpose store Vto[feature][seq]
    int vb = nb - 2560;
#pragma unroll
    for (int i = 0; i < 4; ++i)
#pragma unroll
      for (int j = 0; j < 4; ++j)
#pragma unroll
        for (int r = 0; r < 4; ++r)
          Vto[(size_t)(vb + 16 * j + lr) * S_LEN + mb + 16 * i + rsub + r] =
              (__bf16)acc[i][j][r];
  }
}

// ---------------- output GEMM: C[M,N] = A[M,K] @ B[N,K]^T, f32 out ----------
__global__ __launch_bounds__(256) void gemm_out(const __bf16* __restrict__ A,
                                                const __bf16* __restrict__ B,
                                                float* __restrict__ out,
                                                int M, int N, int K) {
  __shared__ __align__(16) __bf16 Abuf[128 * 32];
  __shared__ __align__(16) __bf16 Bbuf[128 * 32];
  const int tid = threadIdx.x;
  const int w = tid >> 6, l = tid & 63;
  const int wr = w >> 1, wc = w & 1;
  const int row0 = blockIdx.y * 128, col0 = blockIdx.x * 128;
  const int lr = l & 15, lk = (l >> 4) * 8;

  f32x4 acc[4][4] = {};

  const __bf16* Ag = A + (size_t)(row0 + (tid >> 2)) * K + (tid & 3) * 8;
  const __bf16* Bg = B + (size_t)(col0 + (tid >> 2)) * K + (tid & 3) * 8;
  __bf16* AbufW = Abuf + w * 512;
  __bf16* BbufW = Bbuf + w * 512;

  for (int kt = 0; kt < K; kt += 32) {
    gload_lds16(Ag + kt, AbufW);
    gload_lds16(Ag + kt + (size_t)64 * K, AbufW + 2048);
    gload_lds16(Bg + kt, BbufW);
    gload_lds16(Bg + kt + (size_t)64 * K, BbufW + 2048);
    __syncthreads();
    bf16x8 af[4], bfr[4];
#pragma unroll
    for (int i = 0; i < 4; ++i)
      af[i] = *reinterpret_cast<const bf16x8*>(&Abuf[(64 * wr + 16 * i + lr) * 32 + lk]);
#pragma unroll
    for (int j = 0; j < 4; ++j)
      bfr[j] = *reinterpret_cast<const bf16x8*>(&Bbuf[(64 * wc + 16 * j + lr) * 32 + lk]);
#pragma unroll
    for (int i = 0; i < 4; ++i)
#pragma unroll
      for (int j = 0; j < 4; ++j)
        acc[i][j] = mfma16(af[i], bfr[j], acc[i][j]);
    __syncthreads();
  }

  const int mb = row0 + 64 * wr, nb = col0 + 64 * wc;
  const int rsub = (l >> 4) * 4;
#pragma unroll
  for (int i = 0; i < 4; ++i)
#pragma unroll
    for (int j = 0; j < 4; ++j)
#pragma unroll
      for (int r = 0; r < 4; ++r)
        out[(size_t)(mb + 16 * i + rsub + r) * N + nb + 16 * j + lr] = acc[i][j][r];
}

// ---------------- flash attention v2: swapped QK^T, in-register softmax ------
// Q: [S,2048] bf16 (RoPE'd)  Kc: [S,512] bf16 (RoPE'd)  Vt: [512,S] bf16
// AO: [S,2048] bf16. Grid: (16 pairs, 32 heads), 256 thr. Block processes
// q-tiles {p, 31-p} (64 rows each) -> uniform 33 kv-iterations per block.
__global__ __launch_bounds__(256) void attn_k(const __bf16* __restrict__ Q,
                                              const __bf16* __restrict__ Kc,
                                              const __bf16* __restrict__ Vt,
                                              __bf16* __restrict__ AO) {
  const int w = threadIdx.x >> 6, l = threadIdx.x & 63;
  const int lr = l & 15, lg = l >> 4;
  const int pair = blockIdx.x, h = blockIdx.y, kh = h >> 2;

  for (int sel = 0; sel < 2; ++sel) {
    const int t = sel ? (31 - pair) : pair;
    const int qbase = t * 64 + w * 16;
    const __bf16* qp = Q + (size_t)(qbase + lr) * HIDQ + h * HD + lg * 8;
    bf16x8 qf0 = *reinterpret_cast<const bf16x8*>(qp);
    bf16x8 qf1 = *reinterpret_cast<const bf16x8*>(qp + 32);
    f32x4 o[4] = {};
    float mrun = -3e38f, lrun = 0.f;

    for (int it = 0; it <= t; ++it) {
      const int kv0 = it * 64;
      const bool diag = (it == t);
      const int nmax = diag ? (w + 1) : 4;  // wave-uniform

      // QK^T swapped: A = K rows (kv), B = Q rows (q). sc[n][r]:
      //   q = qbase + lr, kv = kv0 + 16n + 4*lg + r
      f32x4 sc[4] = {};
      const __bf16* kp = Kc + (size_t)(kv0 + lr) * HIDK + kh * HD + lg * 8;
#pragma unroll
      for (int n = 0; n < 4; ++n) {
        if (n < nmax) {
          bf16x8 k0 = *reinterpret_cast<const bf16x8*>(kp + (size_t)n * 16 * HIDK);
          bf16x8 k1 = *reinterpret_cast<const bf16x8*>(kp + (size_t)n * 16 * HIDK + 32);
          sc[n] = mfma16(k0, qf0, sc[n]);
          sc[n] = mfma16(k1, qf1, sc[n]);
        }
      }

      // V loads hoisted: latency hides under softmax VALU phase
      bf16x8 vf0[4], vf1[4];
      const __bf16* vp = Vt + (size_t)(kh * HD + lr) * S_LEN + kv0 + lg * 8;
#pragma unroll
      for (int dn = 0; dn < 4; ++dn) {
        vf0[dn] = *reinterpret_cast<const bf16x8*>(vp + (size_t)dn * 16 * S_LEN);
        vf1[dn] = *reinterpret_cast<const bf16x8*>(vp + (size_t)dn * 16 * S_LEN + 32);
      }

      // scale + causal mask + in-register row stats
      float pmax = -3e38f;
#pragma unroll
      for (int n = 0; n < 4; ++n)
#pragma unroll
        for (int r = 0; r < 4; ++r) {
          float v = sc[n][r] * 0.125f;
          if (diag && (kv0 + 16 * n + 4 * lg + r > qbase + lr)) v = -3e38f;
          sc[n][r] = v;
          pmax = fmaxf(pmax, v);
        }
      pmax = fmaxf(pmax, __shfl_xor(pmax, 16));
      pmax = fmaxf(pmax, __shfl_xor(pmax, 32));
      float mnew = fmaxf(mrun, pmax);
      float alpha = __expf(mrun - mnew);
      float psum = 0.f;
#pragma unroll
      for (int n = 0; n < 4; ++n)
#pragma unroll
        for (int r = 0; r < 4; ++r) {
          float pv = __expf(sc[n][r] - mnew);
          sc[n][r] = pv;
          psum += pv;
        }
      psum += __shfl_xor(psum, 16);
      psum += __shfl_xor(psum, 32);
      lrun = lrun * alpha + psum;
      mrun = mnew;
#pragma unroll
      for (int dn = 0; dn < 4; ++dn) o[dn] *= alpha;

      // pack P to bf16 words: W0[n][rp] = (p[16n+4lg+2rp], p[..+1])
      unsigned int W0[4][2];
#pragma unroll
      for (int n = 0; n < 4; ++n) {
        W0[n][0] = packbf(sc[n][0], sc[n][1]);
        W0[n][1] = packbf(sc[n][2], sc[n][3]);
      }
      // Exchange into PV B-frag layout. Dest lane (lg,lr) word tt needs
      //   pack(P[8*lg+2*tt], P[8*lg+2*tt+1])  (bp0; +32 for bp1)
      // which lives at source lane (2*(lg&1)+(tt>>1))*16+lr in chunk
      //   n = lg>>1 (bp0) / 2+(lg>>1) (bp1), word rp = tt&1.
      // n depends on the DEST lane, so shuffle all chunks and select locally
      // (shfl evaluates the var on the SOURCE lane — selecting pre-shuffle
      // by (lg&2) was the round-2 bug).
      union BP { unsigned int u[4]; bf16x8 v; };
      BP u0, u1;
#pragma unroll
      for (int tt = 0; tt < 4; ++tt) {
        int src = ((lg & 1) * 2 + (tt >> 1)) * 16 + lr;
        unsigned int a0 = __shfl(W0[0][tt & 1], src);
        unsigned int a1 = __shfl(W0[1][tt & 1], src);
        unsigned int a2 = __shfl(W0[2][tt & 1], src);
        unsigned int a3 = __shfl(W0[3][tt & 1], src);
        u0.u[tt] = (lg & 2) ? a1 : a0;
        u1.u[tt] = (lg & 2) ? a3 : a2;
      }
      bf16x8 bp0 = u0.v, bp1 = u1.v;

      // PV: A = V^T rows (d), B = P^T cols (q). o[dn][r]:
      //   q = qbase + lr, d = 16*dn + 4*lg + r
#pragma unroll
      for (int dn = 0; dn < 4; ++dn) {
        o[dn] = mfma16(vf0[dn], bp0, o[dn]);
        o[dn] = mfma16(vf1[dn], bp1, o[dn]);
      }
    }

    float inv = 1.0f / lrun;
    unsigned int* aout =
        (unsigned int*)(AO + (size_t)(qbase + lr) * HIDQ + h * HD);
#pragma unroll
    for (int dn = 0; dn < 4; ++dn) {
      aout[8 * dn + 2 * lg]     = packbf(o[dn][0] * inv, o[dn][1] * inv);
      aout[8 * dn + 2 * lg + 1] = packbf(o[dn][2] * inv, o[dn][3] * inv);
    }
  }
}

extern "C" void kernel_launch(void* const* d_in, const int* in_sizes, int n_in,
                              void* d_out, int out_size, void* d_ws, size_t ws_size,
                              hipStream_t stream) {
  const float* hs  = (const float*)d_in[0];
  const int*   pos = (const int*)d_in[1];
  const float* wq  = (const float*)d_in[2];
  const float* wk  = (const float*)d_in[3];
  const float* wv  = (const float*)d_in[4];
  const float* wo  = (const float*)d_in[5];

  char* ws = (char*)d_ws;
  const size_t MB = (size_t)1 << 20;
  __bf16* Xbf = (__bf16*)(ws + 0 * MB);    // 16 MB [2048 x 4096]
  __bf16* WQb = (__bf16*)(ws + 16 * MB);   // 16 MB [2048 x 4096]  \
  /* WKb = ws+32MB  4 MB [512 x 4096]  | contiguous: B of gemm_qkv (3072 rows) */
  /* WVb = ws+36MB  4 MB [512 x 4096]  / and contiguous cast dst               */
  __bf16* WOb = (__bf16*)(ws + 40 * MB);   //  8 MB [2048 x 2048]
  __bf16* Qb  = (__bf16*)(ws + 48 * MB);   //  8 MB [2048 x 2048]
  __bf16* Kb  = (__bf16*)(ws + 56 * MB);   //  2 MB [2048 x 512]
  __bf16* Vt  = (__bf16*)(ws + 58 * MB);   //  2 MB [512 x 2048]
  __bf16* AOb = (__bf16*)(ws + 60 * MB);   //  8 MB [2048 x 2048]
  float2* CS  = (float2*)(ws + 68 * MB);   // 512 KB [2048 x 32]

  cast_all_k<<<F4_TOT / 256, 256, 0, stream>>>(hs, wq, wk, wv, wo, (bf16x4*)ws);
  rope_table_k<<<(S_LEN * 32) / 256, 256, 0, stream>>>(pos, CS);

  gemm_qkv<<<dim3(3072 / 128, S_LEN / 128), 256, 0, stream>>>(
      Xbf, WQb, Qb, Kb, Vt, CS);

  attn_k<<<dim3(16, NH), 256, 0, stream>>>(Qb, Kb, Vt, AOb);

  gemm_out<<<dim3(HIDQ / 128, S_LEN / 128), 256, 0, stream>>>(
      AOb, WOb, (float*)d_out, S_LEN, HIDQ, HIDQ);
}